// Round 7
// baseline (570.746 us; speedup 1.0000x reference)
//
#include <hip/hip_runtime.h>
#include <hip/hip_bf16.h>

#define EMB 300
#define HID 10
#define BATCH 256
#define SEQ 512
#define G3 30
#define WROWS 24                 // rows (timesteps) per pipeline window
#define NWIN 22                  // ceil(512/24); last window = 8 live rows
#define NITER (NWIN + 2)         // scanner lags 2 windows

__device__ __forceinline__ float fsig(float x) {
    float e = __builtin_amdgcn_exp2f(-1.4426950408889634f * x);
    return __builtin_amdgcn_rcpf(1.0f + e);
}
__device__ __forceinline__ float ftanh(float x) {
    float e = __builtin_amdgcn_exp2f(2.8853900817779268f * x);
    return fmaf(-2.0f, __builtin_amdgcn_rcpf(1.0f + e), 1.0f);
}
__device__ __forceinline__ float rdlane(float v, int lane) {
    return __int_as_float(__builtin_amdgcn_readlane(__float_as_int(v), lane));
}

// ---------------------------------------------------------------------------
// Prep: transposed forward weights wt[301][32]; wt[k][g] = w_ih[g][k] for
// k<300, row 300 = b_ih (bias). Cols 30,31 = 0. One k-row = 128 B contiguous
// -> producer wave reads it as 8 coalesced b128s (one line/k).
// ---------------------------------------------------------------------------
__global__ void k_prep(const float* __restrict__ w_ih,
                       const float* __restrict__ b_ih,
                       float* __restrict__ wt) {
    int i = blockIdx.x * 256 + threadIdx.x;
    if (i >= 301 * 32) return;
    int kk = i >> 5, g = i & 31;
    float v = 0.0f;
    if (g < G3) v = (kk < EMB) ? w_ih[g * EMB + kk] : b_ih[g];
    wt[i] = v;
}

// ---------------------------------------------------------------------------
// Fused kernel: 256 blocks (one per batch element, 1 block/CU), 256 threads.
//   waves 1-3 (192 thr = 24 rows x 8 quads): per window w, compute
//     gi[row][gate] = b_ih + x[row]·w_ih  into ring[w%3]; x from LDS xbuf
//     (stride 300: rows hit distinct bank-quads, conflict-free); weights via
//     coalesced VMEM b128 (vmcnt fine-grained — no s_load/ds_read lgkmcnt mix,
//     the R6 stall). Prefetch x(w+1) into regs in phase A, store in phase B.
//   wave 0: iter 0 = backward-dir single GRU step (h0=0) on x[b,511];
//     iter 1 = fill depth-4 prefetch ring; iter i>=2 = scan window i-2
//     (2-window lag keeps prefetch inside ready ring slots). Epilogue =
//     fused Linear(2H->1).
// ---------------------------------------------------------------------------
__global__ __launch_bounds__(256, 1) void k_fused(
        const float* __restrict__ x,
        const float* __restrict__ wt,
        const float* __restrict__ w_hh,
        const float* __restrict__ b_hh,
        const float* __restrict__ w_ih_b,
        const float* __restrict__ b_ih_b,
        const float* __restrict__ b_hh_b,
        const float* __restrict__ w_lin,
        const float* __restrict__ b_lin,
        float* __restrict__ out) {
    __shared__ float xbuf[WROWS * EMB];        // 28800 B
    __shared__ float ring[3][WROWS * 32];      // 9216 B
    const int b    = blockIdx.x;
    const int t    = threadIdx.x;
    const int wv   = t >> 6;
    const int lane = t & 63;

    // ---- producer ids (waves 1-3) ----
    const int tp   = t - 64;                   // 0..191
    const int prow = (tp >> 3) & 31;           // 0..23
    const int pq   = tp & 7;                   // 0..7
    const float4* __restrict__ wt4 = (const float4*)wt;
    float4 bias4 = {0.f, 0.f, 0.f, 0.f};

    // ---- scanner state (wave 0) ----
    const int jc = (lane < HID) ? lane : HID - 1;
    float wr[HID], wz[HID], wn[HID];
    float br = 0.f, bz = 0.f, bn = 0.f;
    float h = 0.f, hs[HID];
    float pr[4], pz[4], pn[4];
    float hbv = 0.f;
    int rs_off = 0, rs_slot = 0, rs_abs = 0;

    if (wv == 0) {
#pragma unroll
        for (int k = 0; k < HID; k++) {
            hs[k] = 0.f;
            wr[k] = w_hh[jc * HID + k];
            wz[k] = w_hh[(HID + jc) * HID + k];
            wn[k] = w_hh[(2 * HID + jc) * HID + k];
        }
        br = b_hh[jc]; bz = b_hh[HID + jc]; bn = b_hh[2 * HID + jc];
    } else {
        bias4 = wt4[2400 + pq];                // bias row (k=300)
        // prologue: stage x window 0 (rows 0..23, all < 512)
        float4 st[10];
        int idx = 0;
        for (int ii = tp; ii < WROWS * 75; ii += 192, idx++) {
            int r = ii / 75, c = ii - r * 75;
            st[idx] = *(const float4*)(x + ((size_t)b * SEQ + r) * EMB + c * 4);
        }
        idx = 0;
        for (int ii = tp; ii < WROWS * 75; ii += 192, idx++) {
            int r = ii / 75, c = ii - r * 75;
            *(float4*)(xbuf + r * EMB + c * 4) = st[idx];
        }
    }
    __syncthreads();

    for (int i = 0; i < NITER; i++) {
        float4 pf[10];
        int pf_act = 0;
        // ================= phase A =================
        if (wv >= 1) {
            if (i + 1 < NWIN) {                // prefetch x window i+1
                pf_act = 1;
                int idx = 0;
                for (int ii = tp; ii < WROWS * 75; ii += 192, idx++) {
                    int r = ii / 75, c = ii - r * 75;
                    int grow = (i + 1) * WROWS + r;
                    if (grow > SEQ - 1) grow = SEQ - 1;   // window 21 partial
                    pf[idx] = *(const float4*)(x + ((size_t)b * SEQ + grow) * EMB + c * 4);
                }
            }
            if (i < NWIN) {                    // compute gi window i
                float a0 = bias4.x, a1 = bias4.y, a2 = bias4.z, a3 = bias4.w;
                const float4* __restrict__ xb4 = (const float4*)xbuf;
#pragma unroll 5
                for (int k4 = 0; k4 < 75; k4++) {
                    const float4 xv = xb4[prow * 75 + k4];
                    const float4* __restrict__ wp = wt4 + (k4 * 4) * 8 + pq;
                    const float4 w0 = wp[0];
                    const float4 w1 = wp[8];
                    const float4 w2 = wp[16];
                    const float4 w3 = wp[24];
                    a0 = fmaf(xv.x, w0.x, a0); a1 = fmaf(xv.x, w0.y, a1);
                    a2 = fmaf(xv.x, w0.z, a2); a3 = fmaf(xv.x, w0.w, a3);
                    a0 = fmaf(xv.y, w1.x, a0); a1 = fmaf(xv.y, w1.y, a1);
                    a2 = fmaf(xv.y, w1.z, a2); a3 = fmaf(xv.y, w1.w, a3);
                    a0 = fmaf(xv.z, w2.x, a0); a1 = fmaf(xv.z, w2.y, a1);
                    a2 = fmaf(xv.z, w2.z, a2); a3 = fmaf(xv.z, w2.w, a3);
                    a0 = fmaf(xv.w, w3.x, a0); a1 = fmaf(xv.w, w3.y, a1);
                    a2 = fmaf(xv.w, w3.z, a2); a3 = fmaf(xv.w, w3.w, a3);
                }
                float4 o = {a0, a1, a2, a3};
                *(float4*)(&ring[i % 3][prow * 32 + pq * 4]) = o;
            }
        } else {
            if (i == 0) {
                // backward direction = ONE GRU step on x[b,511], h0 = 0
                const int u = lane;
                const int uc = (u < G3) ? u : G3 - 1;
                const float* __restrict__ xr  = x + ((size_t)b * SEQ + (SEQ - 1)) * EMB;
                const float* __restrict__ wrb = w_ih_b + (size_t)uc * EMB;
                float c0 = 0.f, c1 = 0.f, c2 = 0.f, c3 = 0.f;
                for (int p = 0; p < 75; p++) {
                    const float4 xv  = *(const float4*)(xr + p * 4);
                    const float4 wvv = *(const float4*)(wrb + p * 4);
                    c0 = fmaf(xv.x, wvv.x, c0); c1 = fmaf(xv.y, wvv.y, c1);
                    c2 = fmaf(xv.z, wvv.z, c2); c3 = fmaf(xv.w, wvv.w, c3);
                }
                const float acc = (c0 + c1) + (c2 + c3) + b_ih_b[uc];
                const int ub = (u < HID) ? u : 0;
                const float i_z = __shfl(acc, ub + HID, 64);
                const float i_n = __shfl(acc, ub + 2 * HID, 64);
                if (u < HID) {
                    const float rg = fsig(acc + b_hh_b[u]);
                    const float zg = fsig(i_z + b_hh_b[HID + u]);
                    const float ng = ftanh(fmaf(rg, b_hh_b[2 * HID + u], i_n));
                    hbv = (1.f - zg) * ng;
                }
            } else if (i == 1) {
                // fill depth-4 prefetch ring from window 0 (ready)
#pragma unroll
                for (int d = 0; d < 4; d++) {
                    pr[d] = ring[0][d * 32 + jc];
                    pz[d] = ring[0][d * 32 + HID + jc];
                    pn[d] = ring[0][d * 32 + 2 * HID + jc];
                }
                rs_abs = 4; rs_off = 4; rs_slot = 0;
            } else {
                const int w   = i - 2;
                const int cnt = (w == NWIN - 1) ? (SEQ - (NWIN - 1) * WROWS) : WROWS;
                int s = w * WROWS;
                for (int d = 0; d < cnt; d++) {
                    const int sl = s & 3;
                    const float ir = pr[sl], iz = pz[sl], in_ = pn[sl];
                    // refill from step rs_abs (<= end of window i-1: ready)
                    const float* __restrict__ gp = &ring[rs_slot][rs_off * 32];
                    pr[sl] = gp[jc];
                    pz[sl] = gp[HID + jc];
                    pn[sl] = gp[2 * HID + jc];
                    if (rs_abs < SEQ - 1) {
                        rs_abs++; rs_off++;
                        if (rs_off == WROWS) {
                            rs_off = 0;
                            rs_slot = (rs_slot == 2) ? 0 : rs_slot + 1;
                        }
                    }
                    float ar0 = ir + br, ar1 = 0.f;
                    float az0 = iz + bz, az1 = 0.f;
                    float an0 = bn,      an1 = 0.f;
#pragma unroll
                    for (int k = 0; k < 5; k++) {
                        ar0 = fmaf(wr[k], hs[k], ar0);
                        az0 = fmaf(wz[k], hs[k], az0);
                        an0 = fmaf(wn[k], hs[k], an0);
                        ar1 = fmaf(wr[k + 5], hs[k + 5], ar1);
                        az1 = fmaf(wz[k + 5], hs[k + 5], az1);
                        an1 = fmaf(wn[k + 5], hs[k + 5], an1);
                    }
                    const float rg = fsig(ar0 + ar1);
                    const float zg = fsig(az0 + az1);
                    const float ng = ftanh(fmaf(rg, an0 + an1, in_));
                    h = fmaf(zg, h - ng, ng);          // (1-z)*n + z*h
#pragma unroll
                    for (int k = 0; k < HID; k++) hs[k] = rdlane(h, k);
                    s++;
                }
            }
        }
        __syncthreads();        // barrier1: ring[i%3] written; xbuf reads done
        // ================= phase B =================
        if (wv >= 1 && pf_act) {
            int idx = 0;
            for (int ii = tp; ii < WROWS * 75; ii += 192, idx++) {
                int r = ii / 75, c = ii - r * 75;
                *(float4*)(xbuf + r * EMB + c * 4) = pf[idx];
            }
        }
        __syncthreads();        // barrier2: xbuf(i+1) ready
    }

    // ---- epilogue: fused Linear(2H -> 1), wave 0 ----
    if (wv == 0) {
        const float p = fmaf(w_lin[jc], h, w_lin[HID + jc] * hbv);
        float s = 0.f;
#pragma unroll
        for (int k = 0; k < HID; k++) s += rdlane(p, k);
        if (lane == 0) out[b] = s + b_lin[0];
    }
}

// ---------------------------------------------------------------------------
extern "C" void kernel_launch(void* const* d_in, const int* in_sizes, int n_in,
                              void* d_out, int out_size, void* d_ws, size_t ws_size,
                              hipStream_t stream) {
    const float* x      = (const float*)d_in[0];
    const float* w_ih_f = (const float*)d_in[1];
    const float* w_hh_f = (const float*)d_in[2];
    const float* b_ih_f = (const float*)d_in[3];
    const float* b_hh_f = (const float*)d_in[4];
    const float* w_ih_b = (const float*)d_in[5];
    const float* w_hh_b = (const float*)d_in[6];   // unused: backward is one step, h0=0
    const float* b_ih_b = (const float*)d_in[7];
    const float* b_hh_b = (const float*)d_in[8];
    const float* w_lin  = (const float*)d_in[9];
    const float* b_lin  = (const float*)d_in[10];
    float* out = (float*)d_out;

    float* wt = (float*)d_ws;                      // [301][32] fp32 (38,528 B)
    (void)w_hh_b; (void)in_sizes; (void)n_in; (void)out_size; (void)ws_size;

    k_prep <<<(301 * 32 + 255) / 256, 256, 0, stream>>>(w_ih_f, b_ih_f, wt);
    k_fused<<<BATCH, 256, 0, stream>>>(x, wt, w_hh_f, b_hh_f,
                                       w_ih_b, b_ih_b, b_hh_b, w_lin, b_lin, out);
}